// Round 7
// baseline (313.789 us; speedup 1.0000x reference)
//
#include <hip/hip_runtime.h>

#define NCOLS 128
#define BROWS 128            // rows per bucket
#define CAP   3072           // element capacity per bucket (mean 2560 + 10 sigma)
#define TILE  8192           // elements per bin tile (256 thr x 32)
#define NBMAX 800
#define OVCAP 65536

// ===================== bucket binning with LDS-staged coalesced flush =====================
__global__ void __launch_bounds__(256)
bin_kernel(const int* __restrict__ rows, const int* __restrict__ cols,
           const float* __restrict__ vals, int nnz, int nbuck,
           int2* __restrict__ scratch, int* __restrict__ bcur,
           int3* __restrict__ ovlist, int* __restrict__ ovcur) {
    __shared__ int2 stage[TILE];        // 64 KB
    __shared__ int cnt[NBMAX];          // hist, then stage cursor
    __shared__ int loff[NBMAX + 1];     // exclusive scan of cnt
    __shared__ int gbase[NBMAX];        // reserved global run base
    __shared__ int ssum[256];
    int tid = threadIdx.x;
    int tile_base = blockIdx.x * TILE;
    int tile_n = nnz - tile_base;
    if (tile_n > TILE) tile_n = TILE;

    for (int i = tid; i < nbuck; i += 256) cnt[i] = 0;
    __syncthreads();

    int myrow[32];
#pragma unroll
    for (int j = 0; j < 32; ++j) {
        int idx = tile_base + j * 256 + tid;
        int r = (idx < nnz) ? rows[idx] : -1;
        myrow[j] = r;
        if (r >= 0) atomicAdd(&cnt[r >> 7], 1);
    }
    __syncthreads();

    // blocked exclusive scan of cnt[0..nbuck) -> loff (4 buckets per thread)
    int b4 = tid * 4;
    int c0 = 0, c1 = 0, c2 = 0, c3 = 0;
    if (b4 + 0 < nbuck) c0 = cnt[b4 + 0];
    if (b4 + 1 < nbuck) c1 = cnt[b4 + 1];
    if (b4 + 2 < nbuck) c2 = cnt[b4 + 2];
    if (b4 + 3 < nbuck) c3 = cnt[b4 + 3];
    int s = c0 + c1 + c2 + c3;
    ssum[tid] = s;
    __syncthreads();
    for (int st = 1; st < 256; st <<= 1) {
        int v = (tid >= st) ? ssum[tid - st] : 0;
        __syncthreads();
        ssum[tid] += v;
        __syncthreads();
    }
    int excl = ssum[tid] - s;
    if (b4 + 0 < nbuck) loff[b4 + 0] = excl;
    if (b4 + 1 < nbuck) loff[b4 + 1] = excl + c0;
    if (b4 + 2 < nbuck) loff[b4 + 2] = excl + c0 + c1;
    if (b4 + 3 < nbuck) loff[b4 + 3] = excl + c0 + c1 + c2;
    if (tid == 0) loff[nbuck] = tile_n;
    __syncthreads();

    // reserve global runs; convert cnt into stage cursor (= loff)
    for (int b = tid; b < nbuck; b += 256) {
        int cb = cnt[b];
        gbase[b] = (cb > 0) ? atomicAdd(&bcur[b], cb) : 0;
        cnt[b] = loff[b];
    }
    __syncthreads();

    // place pairs into stage grouped by bucket
#pragma unroll
    for (int j = 0; j < 32; ++j) {
        int r = myrow[j];
        if (r < 0) continue;
        int idx = tile_base + j * 256 + tid;
        int b = r >> 7;
        int lp = atomicAdd(&cnt[b], 1);
        stage[lp] = make_int2(((r & 127) << 17) | cols[idx],
                              __float_as_int(vals[idx]));
    }
    __syncthreads();

    // coalesced flush; recover bucket by binary search in loff
    for (int i = tid; i < tile_n; i += 256) {
        int lo = 0, hi = nbuck;
        while (hi - lo > 1) {
            int mid = (lo + hi) >> 1;
            if (loff[mid] <= i) lo = mid; else hi = mid;
        }
        int b = lo;
        int pos = gbase[b] + (i - loff[b]);
        int2 pr = stage[i];
        if (pos < CAP) {
            scratch[(size_t)b * CAP + pos] = pr;
        } else {
            int o = atomicAdd(ovcur, 1);
            if (o < OVCAP) {
                int r = b * BROWS + (pr.x >> 17);
                ovlist[o] = make_int3(r, pr.x & 0x1FFFF, pr.y);
            }
        }
    }
}

// One block per bucket: LDS-stage, histogram by local row, scan, place in-place.
__global__ void __launch_bounds__(256)
sort_bucket_kernel(int2* __restrict__ scratch, const int* __restrict__ bcur,
                   int* __restrict__ row_start, int* __restrict__ row_end,
                   int M) {
    __shared__ int2 stage[CAP];
    __shared__ int cnt[BROWS];
    __shared__ int off[BROWS];
    int b = blockIdx.x;
    int tid = threadIdx.x;
    int n = bcur[b];
    if (n > CAP) n = CAP;
    size_t base = (size_t)b * CAP;

    for (int i = tid; i < n; i += 256) stage[i] = scratch[base + i];
    if (tid < BROWS) cnt[tid] = 0;
    __syncthreads();

    for (int i = tid; i < n; i += 256) atomicAdd(&cnt[stage[i].x >> 17], 1);
    __syncthreads();

    if (tid < BROWS) off[tid] = cnt[tid];
    __syncthreads();
    for (int s = 1; s < BROWS; s <<= 1) {
        int v = 0;
        if (tid < BROWS && tid >= s) v = off[tid - s];
        __syncthreads();
        if (tid < BROWS) off[tid] += v;
        __syncthreads();
    }

    if (tid < BROWS) {
        int r = b * BROWS + tid;
        int excl = off[tid] - cnt[tid];
        if (r < M) {
            row_start[r] = (int)(base + excl);
            row_end[r]   = (int)(base + off[tid]);
        }
        off[tid] = excl;
    }
    __syncthreads();

    for (int i = tid; i < n; i += 256) {
        int lr = stage[i].x >> 17;
        int p = atomicAdd(&off[lr], 1);
        scratch[base + p] = stage[i];
    }
}

// Handle (astronomically rare) bucket-capacity overflow via atomics, after spmm.
__global__ void __launch_bounds__(256)
overflow_kernel(const int3* __restrict__ ovlist, const int* __restrict__ ovcur,
                const float* __restrict__ dense, float* __restrict__ out) {
    int n = *ovcur;
    if (n > OVCAP) n = OVCAP;
    int tid = blockIdx.x * blockDim.x + threadIdx.x;
    int nth = gridDim.x * blockDim.x;
    for (int e = tid >> 5; e < n; e += nth >> 5) {
        int3 t = ovlist[e];
        float v = __int_as_float(t.z);
        int chunk = tid & 31;
        const float4 d =
            reinterpret_cast<const float4*>(dense + (size_t)t.y * NCOLS)[chunk];
        float* o = out + (size_t)t.x * NCOLS + chunk * 4;
        atomicAdd(o + 0, v * d.x);
        atomicAdd(o + 1, v * d.y);
        atomicAdd(o + 2, v * d.z);
        atomicAdd(o + 3, v * d.w);
    }
}

// CSR SpMM: one wave64 per row, 8 nnz in flight (p = lane>>3), 8 lanes x 16 cols.
__global__ void __launch_bounds__(256)
csr_spmm_kernel(const int* __restrict__ row_start, const int* __restrict__ row_end,
                const int2* __restrict__ spair, const float* __restrict__ dense,
                float* __restrict__ out, int M) {
    int wid = threadIdx.x >> 6;
    int lane = threadIdx.x & 63;
    int row = blockIdx.x * 4 + wid;
    if (row >= M) return;

    int start = row_start[row];
    int end = row_end[row];
    int p = lane >> 3;                  // 0..7: which in-flight nnz
    int ch = lane & 7;                  // 0..7: float4 sub-chunk

    float4 a0 = make_float4(0.f, 0.f, 0.f, 0.f);
    float4 a1 = make_float4(0.f, 0.f, 0.f, 0.f);
    float4 a2 = make_float4(0.f, 0.f, 0.f, 0.f);
    float4 a3 = make_float4(0.f, 0.f, 0.f, 0.f);

    int kk = start + p;
    int c = 0;
    float v = 0.f;
    if (kk < end) {
        int2 t = spair[kk];
        c = t.x & 0x1FFFF;
        v = __int_as_float(t.y);
    }

    for (int k = start; k < end; k += 8) {
        int kn = k + 8 + p;
        int cn = 0;
        float vn = 0.f;
        if (kn < end) {
            int2 t = spair[kn];
            cn = t.x & 0x1FFFF;
            vn = __int_as_float(t.y);
        }
        const float4* drow =
            reinterpret_cast<const float4*>(dense) + (size_t)c * (NCOLS / 4);
        float4 d0 = drow[ch];
        float4 d1 = drow[ch + 8];
        float4 d2 = drow[ch + 16];
        float4 d3 = drow[ch + 24];
        a0.x += v * d0.x; a0.y += v * d0.y; a0.z += v * d0.z; a0.w += v * d0.w;
        a1.x += v * d1.x; a1.y += v * d1.y; a1.z += v * d1.z; a1.w += v * d1.w;
        a2.x += v * d2.x; a2.y += v * d2.y; a2.z += v * d2.z; a2.w += v * d2.w;
        a3.x += v * d3.x; a3.y += v * d3.y; a3.z += v * d3.z; a3.w += v * d3.w;
        c = cn;
        v = vn;
    }

#pragma unroll
    for (int off = 8; off <= 32; off <<= 1) {
        a0.x += __shfl_xor(a0.x, off, 64); a0.y += __shfl_xor(a0.y, off, 64);
        a0.z += __shfl_xor(a0.z, off, 64); a0.w += __shfl_xor(a0.w, off, 64);
        a1.x += __shfl_xor(a1.x, off, 64); a1.y += __shfl_xor(a1.y, off, 64);
        a1.z += __shfl_xor(a1.z, off, 64); a1.w += __shfl_xor(a1.w, off, 64);
        a2.x += __shfl_xor(a2.x, off, 64); a2.y += __shfl_xor(a2.y, off, 64);
        a2.z += __shfl_xor(a2.z, off, 64); a2.w += __shfl_xor(a2.w, off, 64);
        a3.x += __shfl_xor(a3.x, off, 64); a3.y += __shfl_xor(a3.y, off, 64);
        a3.z += __shfl_xor(a3.z, off, 64); a3.w += __shfl_xor(a3.w, off, 64);
    }

    if (p == 0) {
        float4* orow = reinterpret_cast<float4*>(out) + (size_t)row * (NCOLS / 4);
        orow[ch] = a0;
        orow[ch + 8] = a1;
        orow[ch + 16] = a2;
        orow[ch + 24] = a3;
    }
}

// ===================== fallback level 2: proven CSR path =====================
__global__ void __launch_bounds__(256)
hist_kernel(const int* __restrict__ rows, int* __restrict__ counts, int nnz) {
    int i = blockIdx.x * 256 + threadIdx.x;
    if (i < nnz) atomicAdd(&counts[rows[i]], 1);
}

__global__ void __launch_bounds__(256)
block_reduce_kernel(const int* __restrict__ counts, int* __restrict__ bsums,
                    int M) {
    __shared__ int lds[256];
    int b = blockIdx.x, t = threadIdx.x;
    int base = b * 1024 + t * 4;
    int s = 0;
#pragma unroll
    for (int j = 0; j < 4; ++j)
        if (base + j < M) s += counts[base + j];
    lds[t] = s;
    __syncthreads();
    for (int off = 128; off > 0; off >>= 1) {
        if (t < off) lds[t] += lds[t + off];
        __syncthreads();
    }
    if (t == 0) bsums[b] = lds[0];
}

__global__ void __launch_bounds__(1024)
scan_bsums_kernel(int* __restrict__ bsums, int NB) {
    __shared__ int lds[1024];
    int t = threadIdx.x;
    int x = (t < NB) ? bsums[t] : 0;
    lds[t] = x;
    __syncthreads();
    for (int off = 1; off < 1024; off <<= 1) {
        int v = (t >= off) ? lds[t - off] : 0;
        __syncthreads();
        lds[t] += v;
        __syncthreads();
    }
    if (t < NB) bsums[t] = lds[t] - x;
}

__global__ void __launch_bounds__(256)
offsets_kernel(const int* __restrict__ counts, const int* __restrict__ bsums,
               int* __restrict__ row_start, int* __restrict__ row_endx,
               int* __restrict__ cursor, int M, int nnz) {
    __shared__ int lds[256];
    int b = blockIdx.x, t = threadIdx.x;
    int base = b * 1024 + t * 4;
    int c0 = 0, c1 = 0, c2 = 0, c3 = 0;
    if (base + 0 < M) c0 = counts[base + 0];
    if (base + 1 < M) c1 = counts[base + 1];
    if (base + 2 < M) c2 = counts[base + 2];
    if (base + 3 < M) c3 = counts[base + 3];
    int s = c0 + c1 + c2 + c3;
    lds[t] = s;
    __syncthreads();
    for (int off = 1; off < 256; off <<= 1) {
        int v = (t >= off) ? lds[t - off] : 0;
        __syncthreads();
        lds[t] += v;
        __syncthreads();
    }
    int off0 = bsums[b] + lds[t] - s;
    int e0 = off0, e1 = off0 + c0, e2 = e1 + c1, e3 = e2 + c2;
    if (base + 0 < M) { row_start[base + 0] = e0; row_endx[base + 0] = e1; cursor[base + 0] = e0; }
    if (base + 1 < M) { row_start[base + 1] = e1; row_endx[base + 1] = e2; cursor[base + 1] = e1; }
    if (base + 2 < M) { row_start[base + 2] = e2; row_endx[base + 2] = e3; cursor[base + 2] = e2; }
    if (base + 3 < M) { row_start[base + 3] = e3; row_endx[base + 3] = e3 + c3; cursor[base + 3] = e3; }
}

__global__ void __launch_bounds__(256)
scatter_kernel(const int* __restrict__ rows, const int* __restrict__ cols,
               const float* __restrict__ vals, int* __restrict__ cursor,
               int2* __restrict__ spair, int nnz) {
    int i = blockIdx.x * 256 + threadIdx.x;
    if (i >= nnz) return;
    int r = rows[i];
    int pos = atomicAdd(&cursor[r], 1);
    spair[pos] = make_int2(cols[i] & 0x1FFFF, __float_as_int(vals[i]));
}

// ===================== fallback level 3: atomic =====================
__global__ void __launch_bounds__(256)
spmm_atomic_kernel(const int* __restrict__ rows, const int* __restrict__ cols,
                   const float* __restrict__ vals, const float* __restrict__ dense,
                   float* __restrict__ out, int nnz) {
    long long tid = (long long)blockIdx.x * blockDim.x + threadIdx.x;
    int i = (int)(tid >> 5);
    int chunk = (int)(tid & 31);
    if (i >= nnz) return;
    int r = rows[i];
    int c = cols[i];
    float v = vals[i];
    const float4 d =
        reinterpret_cast<const float4*>(dense + (size_t)c * NCOLS)[chunk];
    float* o = out + (size_t)r * NCOLS + (size_t)chunk * 4;
    atomicAdd(o + 0, v * d.x);
    atomicAdd(o + 1, v * d.y);
    atomicAdd(o + 2, v * d.z);
    atomicAdd(o + 3, v * d.w);
}

// ===================== host =====================
extern "C" void kernel_launch(void* const* d_in, const int* in_sizes, int n_in,
                              void* d_out, int out_size, void* d_ws, size_t ws_size,
                              hipStream_t stream) {
    const int*   idx   = (const int*)d_in[0];
    const float* vals  = (const float*)d_in[1];
    const float* dense = (const float*)d_in[2];
    float*       out   = (float*)d_out;

    const int nnz = in_sizes[1];
    const int* rows = idx;
    const int* cols = idx + nnz;
    const int M = out_size / NCOLS;
    const int nbuck = (M + BROWS - 1) / BROWS;

    size_t o_scratch = 0;                                    // int2 [nbuck*CAP]
    size_t o_ovlist  = o_scratch + (size_t)nbuck * CAP * 8;  // int3 [OVCAP]
    size_t o_bcur    = o_ovlist + (size_t)OVCAP * 12;        // int [nbuck]
    size_t o_ovcur   = o_bcur + (size_t)nbuck * 4;           // int
    size_t o_rs      = o_ovcur + 4;                          // int [M]
    size_t o_re      = o_rs + (size_t)M * 4;                 // int [M]
    size_t need_new  = o_re + (size_t)M * 4;

    if (need_new <= ws_size && nbuck <= NBMAX) {
        char* ws = (char*)d_ws;
        int2* scratch   = (int2*)(ws + o_scratch);
        int3* ovlist    = (int3*)(ws + o_ovlist);
        int*  bcur      = (int*)(ws + o_bcur);
        int*  ovcur     = (int*)(ws + o_ovcur);
        int*  row_start = (int*)(ws + o_rs);
        int*  row_end   = (int*)(ws + o_re);

        hipMemsetAsync(bcur, 0, (size_t)(nbuck + 1) * 4, stream);  // bcur + ovcur
        int ntile = (nnz + TILE - 1) / TILE;
        bin_kernel<<<ntile, 256, 0, stream>>>(rows, cols, vals, nnz, nbuck,
                                              scratch, bcur, ovlist, ovcur);
        sort_bucket_kernel<<<nbuck, 256, 0, stream>>>(scratch, bcur, row_start,
                                                      row_end, M);
        csr_spmm_kernel<<<(M + 3) / 4, 256, 0, stream>>>(row_start, row_end,
                                                         scratch, dense, out, M);
        overflow_kernel<<<32, 256, 0, stream>>>(ovlist, ovcur, dense, out);
        return;
    }

    const int NB = (M + 1023) / 1024;
    size_t f_spair  = 0;
    size_t f_counts = f_spair + 2 * (size_t)nnz;
    size_t f_cursor = f_counts + (size_t)M;
    size_t f_rs     = f_cursor + (size_t)M;
    size_t f_re     = f_rs + (size_t)M;
    size_t f_bsums  = f_re + (size_t)M;
    size_t need_old = (f_bsums + (size_t)NB) * 4;

    if (need_old <= ws_size && NB <= 1024) {
        int* wsI = (int*)d_ws;
        int2* spair     = (int2*)(wsI + f_spair);
        int*  counts    = wsI + f_counts;
        int*  cursor    = wsI + f_cursor;
        int*  row_start = wsI + f_rs;
        int*  row_end   = wsI + f_re;
        int*  bsums     = wsI + f_bsums;

        hipMemsetAsync(counts, 0, (size_t)M * 4, stream);
        hist_kernel<<<(nnz + 255) / 256, 256, 0, stream>>>(rows, counts, nnz);
        block_reduce_kernel<<<NB, 256, 0, stream>>>(counts, bsums, M);
        scan_bsums_kernel<<<1, 1024, 0, stream>>>(bsums, NB);
        offsets_kernel<<<NB, 256, 0, stream>>>(counts, bsums, row_start, row_end,
                                               cursor, M, nnz);
        scatter_kernel<<<(nnz + 255) / 256, 256, 0, stream>>>(rows, cols, vals,
                                                              cursor, spair, nnz);
        csr_spmm_kernel<<<(M + 3) / 4, 256, 0, stream>>>(row_start, row_end,
                                                         spair, dense, out, M);
        return;
    }

    hipMemsetAsync(d_out, 0, (size_t)out_size * sizeof(float), stream);
    const long long total = (long long)nnz * 32;
    spmm_atomic_kernel<<<(int)((total + 255) / 256), 256, 0, stream>>>(
        rows, cols, vals, dense, out, nnz);
}